// Round 7
// baseline (1995.319 us; speedup 1.0000x reference)
//
#include <hip/hip_runtime.h>

// Problem constants
#define B_    64
#define T_    512
#define KDIM  1024
#define HID_  1024

// R19 GEMM geometry: 64x32 tile, 128 threads (2 waves), 4x4/thread, BK=16,
// THREE LDS buffers with commit-2-ahead (cross-barrier read prefetch).
#define BM 64     // t rows per block
#define BN 32     // h cols per block
#define BK 16     // one numpy 16-k block per slice
#define LDAA 16   // A region: unpadded (A reads are broadcasts; writes conflict-free)
#define LDAB 20   // B region: padded (5-quad row stride -> conflict-free reads)
#define NSL 64    // slices per block = KDIM/BK
#define BNOFF 1024  // B region offset within a buffer (64*16 floats)
#define BUFSZ 1664  // per-buffer floats: A 64x16 + B 32x20
// total smem = 3*1664 = 4992 floats = 19968 B -> 8 blocks/CU by LDS

// f32 correctly rounded from python float math.exp(-1.0/20.0)
#define ALPHA_F 0.95122942450071400909f

typedef float v4f __attribute__((ext_vector_type(4)));
typedef float v2f __attribute__((ext_vector_type(2)));

// Bit-faithful replication of the harness numpy f32 reference: per output
// element 4 f32 accumulator lanes (lane l sums k = l mod 4), 16-k blocks
// ascending (slices ascending), q descending within block, mul/add separately
// rounded (no FMA), hadd tree (l0+l1)+(l2+l3), one f32 bias add (in the scan
// kernel, same rounding position), f32 scan. Chain identical to R6..R18
// (R16/R17/R18 PASSED with this exact split).
//
// R19 vs R17 (GEMM 1430 us, VALUBusy 80.5%) / R18 (1555, 71%): busy time is
// ~constant (1104-1151 us) across R12/R17/R18 — only the IDLE moves, and it
// tracks resident blocks (5 blk 71%, 10 blk 80.5%). Residual idle is
// structural: with 2 LDS buffers a slice's ds_reads cannot start until the
// barrier that publishes its buffer (and __syncthreads drains all DS ops),
// so every phase restarts with read latency. Fix: 3-buffer rotation —
// compute buf[s%3], PREFETCH slice s+1's q=3 fragments from buf[(s+1)%3]
// (committed one phase earlier) BEFORE the barrier, commit slice s+2 into
// buf[(s+2)%3], global-load slice s+3. Reads now flow across barriers.
// Paid for by dropping the A pad: A reads are broadcast (bank-irrelevant)
// and LDAA=16 makes A-write phases cover all 8 quad-banks -> conflict-free
// (kills most of R17's 5e7 conflicts too). Buffer 6.66 KB, x3 = 19.97 KB ->
// 8 blocks/CU. B keeps LDAB=20 (conflict-free reads; writes 1-collision per
// phase ~ free per R18).
__global__ __launch_bounds__(128, 2) void snn_gemm_np(
    const float* __restrict__ x,     // [B,T,K] f32
    const float* __restrict__ W,     // [H,K] f32
    float* __restrict__ Iout)        // [B,T,H] f32 out (I, no bias)
{
#pragma clang fp contract(off)       // numpy SSE path has no FMA: mul+add only
    __shared__ float smem[3 * BUFSZ];   // 19968 B

    const int tid = threadIdx.x;
    const int bb  = blockIdx.x;         // batch index
    const int t0  = blockIdx.y * BM;    // t tile origin
    const int h0  = blockIdx.z * BN;    // h tile origin

    const int tx = tid & 7;             // h micro (4 cols, stride 8)
    const int ty = tid >> 3;            // t micro (4 rows, stride 16)

    const int sr = tid >> 2;            // staging row 0..31
    const int sc = (tid & 3) << 2;      // staging col 0,4,8,12

    const float* xb = x + ((size_t)bb * T_ + t0) * KDIM;
    const float* Wb = W + (size_t)h0 * KDIM;

// load one q-step's fragments (A broadcast rows, B padded rows)
#define LOADFRAG(AF, BF, BASE, QC)                                         \
    {                                                                      \
        _Pragma("unroll")                                                  \
        for (int j = 0; j < 4; ++j)                                        \
            AF[j] = *(const v4f*)&smem[(BASE) + (ty + 16 * j) * LDAA + (QC)]; \
        _Pragma("unroll")                                                  \
        for (int i = 0; i < 4; ++i)                                        \
            BF[i] = *(const v4f*)&smem[(BASE) + BNOFF + (tx + 8 * i) * LDAB + (QC)]; \
    }

// numpy 4-lane MAC: packed rounded muls then packed rounded adds, lanes
// (0,1) in p01 and (2,3) in p23 — bitwise equal to numpy's chained
// a0b0+(a1b1+(a2b2+(a3b3+acc))) per 4-k group
#define MACFRAG(AF, BF)                                                    \
    {                                                                      \
        _Pragma("unroll")                                                  \
        for (int j = 0; j < 4; ++j)                                        \
            _Pragma("unroll")                                              \
            for (int i = 0; i < 4; ++i) {                                  \
                const v2f m01 = AF[j].xy * BF[i].xy;                       \
                const v2f m23 = AF[j].zw * BF[i].zw;                       \
                p01[j][i] = p01[j][i] + m01;                               \
                p23[j][i] = p23[j][i] + m23;                               \
            }                                                              \
    }

    // ---- prologue: slice 0 -> buf0, slice 1 -> buf1, slice 2 -> regs ----
    float4 pa0, pa1, pw;
    pa0 = *(const float4*)&xb[(size_t)sr * KDIM + sc];
    pa1 = *(const float4*)&xb[(size_t)(32 + sr) * KDIM + sc];
    pw  = *(const float4*)&Wb[(size_t)sr * KDIM + sc];
    *(float4*)&smem[sr * LDAA + sc]            = pa0;
    *(float4*)&smem[(32 + sr) * LDAA + sc]     = pa1;
    *(float4*)&smem[BNOFF + sr * LDAB + sc]    = pw;
    pa0 = *(const float4*)&xb[(size_t)sr * KDIM + 16 + sc];
    pa1 = *(const float4*)&xb[(size_t)(32 + sr) * KDIM + 16 + sc];
    pw  = *(const float4*)&Wb[(size_t)sr * KDIM + 16 + sc];
    *(float4*)&smem[BUFSZ + sr * LDAA + sc]         = pa0;
    *(float4*)&smem[BUFSZ + (32 + sr) * LDAA + sc]  = pa1;
    *(float4*)&smem[BUFSZ + BNOFF + sr * LDAB + sc] = pw;
    pa0 = *(const float4*)&xb[(size_t)sr * KDIM + 32 + sc];
    pa1 = *(const float4*)&xb[(size_t)(32 + sr) * KDIM + 32 + sc];
    pw  = *(const float4*)&Wb[(size_t)sr * KDIM + 32 + sc];
    __syncthreads();                    // buf0 + buf1 visible

    // numpy 4-lane accumulators, lane-paired: p01 = lanes {0,1}, p23 = {2,3}
    v2f p01[4][4], p23[4][4];
#pragma unroll
    for (int j = 0; j < 4; ++j)
#pragma unroll
        for (int i = 0; i < 4; ++i) {
            p01[j][i] = (v2f)(0.0f);
            p23[j][i] = (v2f)(0.0f);
        }

    v4f fa[4], fb[4];                   // cross-barrier prefetched q=3 frags
    LOADFRAG(fa, fb, 0, 12);            // slice 0, q=3

    int cur = 0, pre = BUFSZ, wrt = 2 * BUFSZ;

    for (int s = 0; s < NSL; ++s) {
        // 1) commit regs (slice s+2) into wrt — its last readers (slice s-1)
        //    drained before barrier s-1.
        if (s + 2 < NSL) {
            *(float4*)&smem[wrt + sr * LDAA + sc]         = pa0;
            *(float4*)&smem[wrt + (32 + sr) * LDAA + sc]  = pa1;
            *(float4*)&smem[wrt + BNOFF + sr * LDAB + sc] = pw;
        }
        // 2) issue slice s+3 global loads; a whole phase to land.
        if (s + 3 < NSL) {
            const int nk = (s + 3) << 4;
            pa0 = *(const float4*)&xb[(size_t)sr * KDIM + nk + sc];
            pa1 = *(const float4*)&xb[(size_t)(32 + sr) * KDIM + nk + sc];
            pw  = *(const float4*)&Wb[(size_t)sr * KDIM + nk + sc];
        }
        // 3) compute slice s, q = 3..0 (numpy order). q=3 uses fragments
        //    prefetched BEFORE the last barrier — no post-barrier read stall.
        {
            v4f ga[4], gb[4];
            MACFRAG(fa, fb);                              // q=3
            LOADFRAG(ga, gb, cur, 8);  MACFRAG(ga, gb);   // q=2
            LOADFRAG(ga, gb, cur, 4);  MACFRAG(ga, gb);   // q=1
            LOADFRAG(ga, gb, cur, 0);  MACFRAG(ga, gb);   // q=0
        }
        // 4) prefetch next slice's q=3 frags from pre (committed last phase,
        //    published by barrier s-1 — legal to read NOW, before barrier s).
        if (s + 1 < NSL) LOADFRAG(fa, fb, pre, 12);
        __syncthreads();   // drains: commit writes (publish) + our reads of
                           // cur (so phase s+1's commit may overwrite lineage)
        const int tmp = cur; cur = pre; pre = wrt; wrt = tmp;
    }

    // epilogue: hadd (l0+l1)+(l2+l3); store I (bias added in scan kernel)
    float* const Ob = Iout + ((size_t)bb * T_ + t0) * HID_ + h0;
#pragma unroll
    for (int j = 0; j < 4; ++j)
#pragma unroll
        for (int i = 0; i < 4; ++i) {
            const float s01 = p01[j][i].x + p01[j][i].y;
            const float s23 = p23[j][i].x + p23[j][i].y;
            Ob[(ty + 16 * j) * HID_ + tx + 8 * i] = s01 + s23;
        }
#undef LOADFRAG
#undef MACFRAG
}

// LIF scan, in place over the spikes buffer (each thread owns one (b,h)
// column: strictly read-then-overwrite within the thread, no cross-thread
// sharing). Bias added here: It = s + b (same rounding position as the fused
// version's (s01+s23)+b), then mem = alpha*mem + It — chain unchanged.
// 16-deep register prefetch hides HBM/L3 latency (loads are independent of
// the mem recurrence); arrays fully unrolled -> static indices, no scratch.
__global__ __launch_bounds__(256, 2) void snn_scan(
    float* __restrict__ IS,          // in: I (no bias) / out: spikes, in place
    const float* __restrict__ bias,  // [H]
    float* __restrict__ memf)        // [B,H] f32 out
{
#pragma clang fp contract(off)       // alpha*mem + It must be mul then add
    const int gid = blockIdx.x * 256 + threadIdx.x;
    const int b = gid >> 10;
    const int h = gid & (HID_ - 1);
    float* col = IS + (size_t)b * T_ * HID_ + h;
    const float bv = bias[h];
    float mem = 0.0f;

    float cur[16], nxt[16];
#pragma unroll
    for (int k = 0; k < 16; ++k) cur[k] = col[(size_t)k * HID_];

    for (int tg = 0; tg < T_; tg += 16) {
        if (tg + 16 < T_) {
#pragma unroll
            for (int k = 0; k < 16; ++k)
                nxt[k] = col[(size_t)(tg + 16 + k) * HID_];
        }
#pragma unroll
        for (int k = 0; k < 16; ++k) {
            const float It = cur[k] + bv;     // rounded bias add
            const float am = ALPHA_F * mem;   // rounded mul
            mem = am + It;                    // rounded add
            const bool fire = (mem >= 1.0f);
            col[(size_t)(tg + k) * HID_] = fire ? 1.0f : 0.0f;
            if (fire) mem = 0.0f;
        }
#pragma unroll
        for (int k = 0; k < 16; ++k) cur[k] = nxt[k];
    }
    memf[(size_t)b * HID_ + h] = mem;
}

extern "C" void kernel_launch(void* const* d_in, const int* in_sizes, int n_in,
                              void* d_out, int out_size, void* d_ws, size_t ws_size,
                              hipStream_t stream) {
    const float* x    = (const float*)d_in[0];   // [B,T,K] f32
    const float* W    = (const float*)d_in[1];   // [H,K] f32
    const float* bias = (const float*)d_in[2];   // [H] f32
    float* out    = (float*)d_out;
    float* spikes = out;                          // [B,T,H]
    float* memf   = out + (size_t)B_ * T_ * HID_; // [B,H]

    dim3 g1(B_, T_ / BM, HID_ / BN);   // 64 x 8 x 32 = 16384 blocks
    snn_gemm_np<<<g1, dim3(128), 0, stream>>>(x, W, spikes);

    snn_scan<<<dim3((B_ * HID_) / 256), dim3(256), 0, stream>>>(
        spikes, bias, memf);
}

// Round 8
// 1476.218 us; speedup vs baseline: 1.3516x; 1.3516x over previous
//
#include <hip/hip_runtime.h>

// Problem constants
#define B_    64
#define T_    512
#define KDIM  1024
#define HID_  1024

// R20 GEMM geometry: 64x64 tile, 256 threads (4 waves), 4x4/thread, BK=16.
#define BM 64     // t rows per block
#define BN 64     // h cols per block
#define BK 16     // one numpy 16-k block per slice
#define LDA 20    // padded LDS row: 16+4 floats (5 quads, odd -> reads clean)
#define NSL 64    // slices per block = KDIM/BK
#define BNOFF 1280  // B region offset within a buffer (64*20 floats)
#define BUFSZ 2560  // per-buffer floats: A 64x20 + B 64x20
// total smem = 2*2560 = 5120 floats = 20480 B -> 7 blocks/CU by LDS (28 waves)

// f32 correctly rounded from python float math.exp(-1.0/20.0)
#define ALPHA_F 0.95122942450071400909f

typedef float v4f __attribute__((ext_vector_type(4)));
typedef float v2f __attribute__((ext_vector_type(2)));

// Bit-faithful replication of the harness numpy f32 reference: per output
// element 4 f32 accumulator lanes (lane l sums k = l mod 4), 16-k blocks
// ascending (slices ascending), q descending within block, mul/add separately
// rounded (no FMA), hadd tree (l0+l1)+(l2+l3), one f32 bias add (in the scan
// kernel, same rounding position), f32 scan. Chain identical to R6..R19
// (R16..R19 all PASSED with this split).
//
// R20 vs R17 (GEMM 1430 us, VALUBusy 80.5%): instruction census pins R17's
// busy at 874 us irreducible pk-MAC (v_pk_*_f32 is 4cy/wave, FLOP-rate-equal
// to scalar) + ~277 us staging/loop overhead; idle 280 us tracks occupancy.
// (R19's A-pad removal was a bank-arithmetic error: LDAA=16 => rows stride
// 16 mod 32 banks, 8 rows alias 2 quad-sets at distinct addresses -> 4-way
// READ conflicts, 4.14e8 cycles. Row stride must stay odd-in-quads.)
// R20 attacks both reducible terms with one geometry change: 256-thread
// 64x64 tile. Staging per thread halves (1 A + 1 B float4, 2 ds_writes),
// LDS drops to 20.5 KB -> 7 blocks x 4 waves = 28 waves/CU ceiling (vs 20),
// A-traffic per block halves. LDA=20 for BOTH regions: A reads 4 distinct
// odd-quad rows (clean), B reads 16 rows with one 2-way alias (free, m136),
// writes keep the known-1-collision phase (~free, R17/R18 data).
__global__ __launch_bounds__(256, 2) void snn_gemm_np(
    const float* __restrict__ x,     // [B,T,K] f32
    const float* __restrict__ W,     // [H,K] f32
    float* __restrict__ Iout)        // [B,T,H] f32 out (I, no bias)
{
#pragma clang fp contract(off)       // numpy SSE path has no FMA: mul+add only
    __shared__ float smem[2 * BUFSZ];   // 20480 B
    float* const AB0 = smem;            // A @0, B @1280
    float* const AB1 = smem + BUFSZ;

    const int tid = threadIdx.x;
    const int bb  = blockIdx.x;         // batch index
    const int t0  = blockIdx.y * BM;    // t tile origin
    const int h0  = blockIdx.z * BN;    // h tile origin

    const int tx = tid & 15;            // h micro (4 cols, stride 16)
    const int ty = tid >> 4;            // t micro (4 rows, stride 16)

    const int sr = tid >> 2;            // staging row 0..63
    const int sc = (tid & 3) << 2;      // staging col 0,4,8,12

    const float* xb = x + ((size_t)bb * T_ + t0) * KDIM;
    const float* Wb = W + (size_t)h0 * KDIM;

    // ---- prologue: slice 0 -> AB0; slice 1 -> regs ----
    float4 pa, pw;
    pa = *(const float4*)&xb[(size_t)sr * KDIM + sc];
    pw = *(const float4*)&Wb[(size_t)sr * KDIM + sc];
    *(float4*)&AB0[sr * LDA + sc]         = pa;
    *(float4*)&AB0[BNOFF + sr * LDA + sc] = pw;
    pa = *(const float4*)&xb[(size_t)sr * KDIM + 16 + sc];
    pw = *(const float4*)&Wb[(size_t)sr * KDIM + 16 + sc];
    __syncthreads();                    // AB0 visible

    // numpy 4-lane accumulators, lane-paired: p01 = lanes {0,1}, p23 = {2,3}
    v2f p01[4][4], p23[4][4];
#pragma unroll
    for (int j = 0; j < 4; ++j)
#pragma unroll
        for (int i = 0; i < 4; ++i) {
            p01[j][i] = (v2f)(0.0f);
            p23[j][i] = (v2f)(0.0f);
        }

    for (int s = 0; s < NSL; ++s) {
        float* const cb = (s & 1) ? AB1 : AB0;   // compute buffer (slice s)
        float* const nb = (s & 1) ? AB0 : AB1;   // commit target (slice s+1)

        // 1) commit regs (slice s+1) into nb — overlapped with compute;
        //    nb's old readers finished before the previous barrier.
        if (s + 1 < NSL) {
            *(float4*)&nb[sr * LDA + sc]         = pa;
            *(float4*)&nb[BNOFF + sr * LDA + sc] = pw;
        }
        // 2) issue slice s+2 loads; a whole compute phase to land.
        if (s + 2 < NSL) {
            const int nk = (s + 2) << 4;
            pa = *(const float4*)&xb[(size_t)sr * KDIM + nk + sc];
            pw = *(const float4*)&Wb[(size_t)sr * KDIM + nk + sc];
        }
        // 3) compute slice s: one numpy 16-k block; q=3..0 —
        // per-lane acc += a[4q+l]*b[4q+l], mul then add: bitwise equal to
        // numpy's chained a0b0+(a1b1+(a2b2+(a3b3+acc)))
#pragma unroll
        for (int q = 3; q >= 0; --q) {
            const int qc = q << 2;
            v2f a01[4], a23[4], b01[4], b23[4];
#pragma unroll
            for (int j = 0; j < 4; ++j) {
                const v4f a = *(const v4f*)&cb[(ty + 16 * j) * LDA + qc];
                a01[j] = a.xy; a23[j] = a.zw;
            }
#pragma unroll
            for (int i = 0; i < 4; ++i) {
                const v4f b = *(const v4f*)&cb[BNOFF + (tx + 16 * i) * LDA + qc];
                b01[i] = b.xy; b23[i] = b.zw;
            }
#pragma unroll
            for (int j = 0; j < 4; ++j)
#pragma unroll
                for (int i = 0; i < 4; ++i) {
                    const v2f m01 = a01[j] * b01[i];   // packed rounded muls
                    const v2f m23 = a23[j] * b23[i];
                    p01[j][i] = p01[j][i] + m01;       // packed rounded adds
                    p23[j][i] = p23[j][i] + m23;
                }
        }
        __syncthreads();   // slice s reads done; slice s+1 commit visible
    }

    // epilogue: hadd (l0+l1)+(l2+l3); store I (bias added in scan kernel)
    float* const Ob = Iout + ((size_t)bb * T_ + t0) * HID_ + h0;
#pragma unroll
    for (int j = 0; j < 4; ++j)
#pragma unroll
        for (int i = 0; i < 4; ++i) {
            const float s01 = p01[j][i].x + p01[j][i].y;
            const float s23 = p23[j][i].x + p23[j][i].y;
            Ob[(ty + 16 * j) * HID_ + tx + 16 * i] = s01 + s23;
        }
}

// LIF scan, in place over the spikes buffer (each thread owns one (b,h)
// column: strictly read-then-overwrite within the thread, no cross-thread
// sharing). Bias added here: It = s + b (same rounding position as the fused
// version's (s01+s23)+b), then mem = alpha*mem + It — chain unchanged.
// 16-deep register prefetch hides HBM/L3 latency (loads are independent of
// the mem recurrence); arrays fully unrolled -> static indices, no scratch.
__global__ __launch_bounds__(256, 2) void snn_scan(
    float* __restrict__ IS,          // in: I (no bias) / out: spikes, in place
    const float* __restrict__ bias,  // [H]
    float* __restrict__ memf)        // [B,H] f32 out
{
#pragma clang fp contract(off)       // alpha*mem + It must be mul then add
    const int gid = blockIdx.x * 256 + threadIdx.x;
    const int b = gid >> 10;
    const int h = gid & (HID_ - 1);
    float* col = IS + (size_t)b * T_ * HID_ + h;
    const float bv = bias[h];
    float mem = 0.0f;

    float cur[16], nxt[16];
#pragma unroll
    for (int k = 0; k < 16; ++k) cur[k] = col[(size_t)k * HID_];

    for (int tg = 0; tg < T_; tg += 16) {
        if (tg + 16 < T_) {
#pragma unroll
            for (int k = 0; k < 16; ++k)
                nxt[k] = col[(size_t)(tg + 16 + k) * HID_];
        }
#pragma unroll
        for (int k = 0; k < 16; ++k) {
            const float It = cur[k] + bv;     // rounded bias add
            const float am = ALPHA_F * mem;   // rounded mul
            mem = am + It;                    // rounded add
            const bool fire = (mem >= 1.0f);
            col[(size_t)(tg + k) * HID_] = fire ? 1.0f : 0.0f;
            if (fire) mem = 0.0f;
        }
#pragma unroll
        for (int k = 0; k < 16; ++k) cur[k] = nxt[k];
    }
    memf[(size_t)b * HID_ + h] = mem;
}

extern "C" void kernel_launch(void* const* d_in, const int* in_sizes, int n_in,
                              void* d_out, int out_size, void* d_ws, size_t ws_size,
                              hipStream_t stream) {
    const float* x    = (const float*)d_in[0];   // [B,T,K] f32
    const float* W    = (const float*)d_in[1];   // [H,K] f32
    const float* bias = (const float*)d_in[2];   // [H] f32
    float* out    = (float*)d_out;
    float* spikes = out;                          // [B,T,H]
    float* memf   = out + (size_t)B_ * T_ * HID_; // [B,H]

    dim3 g1(B_, T_ / BM, HID_ / BN);   // 64 x 8 x 16 = 8192 blocks
    snn_gemm_np<<<g1, dim3(256), 0, stream>>>(x, W, spikes);

    snn_scan<<<dim3((B_ * HID_) / 256), dim3(256), 0, stream>>>(
        spikes, bias, memf);
}